// Round 1
// baseline (1078.672 us; speedup 1.0000x reference)
//
#include <hip/hip_runtime.h>
#include <stdint.h>

// Lightning attention, non-diagonal part:
//   out[b,h,t,:] = output[b,h,t,:] + exp(-s[h]*((t%64)+1)) * q[b,h,t,:] @ kv[b,h,t/64,:,:]
// b=2, h=32, n=8192, d=e=128, BLOCK=64, NB=n/64=128.
//
// Memory-bound (1.25 GiB traffic, 17.2 GFLOP). Strategy: 1 block per
// (b,h,seq-block); bf16 MFMA 32x32x16 for the 64x128 = Q(64x128)@KV(128x128)
// tile; NO LDS — fragments loaded directly from global in MFMA operand layout
// (B loads are full-128B-row coalesced; Q re-reads hit L1/L2).

#define DD   128   // d
#define EE   128   // e
#define BLK  64    // BLOCK (rows per seq-block)
#define NB   128   // n / BLOCK

typedef short bf16x8 __attribute__((ext_vector_type(8)));
typedef float f32x16 __attribute__((ext_vector_type(16)));

__device__ __forceinline__ short f2bf(float f) {
    // RNE float -> bf16
    uint32_t u = __float_as_uint(f);
    uint32_t r = u + 0x7FFFu + ((u >> 16) & 1u);
    return (short)(r >> 16);
}

__device__ __forceinline__ bf16x8 cvt8(const float4 lo, const float4 hi) {
    bf16x8 r;
    r[0] = f2bf(lo.x); r[1] = f2bf(lo.y); r[2] = f2bf(lo.z); r[3] = f2bf(lo.w);
    r[4] = f2bf(hi.x); r[5] = f2bf(hi.y); r[6] = f2bf(hi.z); r[7] = f2bf(hi.w);
    return r;
}

__global__ __launch_bounds__(256) void la_nondiag(
    const float* __restrict__ q,      // [b,h,n,d]
    const float* __restrict__ outin,  // [b,h,n,e]
    const float* __restrict__ s,      // [h]
    const float* __restrict__ kv,     // [b,h,NB,d,e]
    float* __restrict__ out,          // [b,h,n,e]
    int h)
{
    const int bid   = blockIdx.x;        // 0 .. b*h*NB-1
    const int mb    = bid & (NB - 1);    // seq-block index
    const int bh    = bid >> 7;          // (b*h) index  (NB==128 -> >>7)
    const int hh    = bh % h;

    const int tid  = threadIdx.x;
    const int wave = tid >> 6;
    const int lane = tid & 63;
    const int half = lane >> 5;          // 0/1
    const int l31  = lane & 31;

    const float sh = s[hh];

    const size_t tile_off = ((size_t)bh * (NB * BLK) + (size_t)mb * BLK);
    const float* qt  = q     + tile_off * DD;
    const float* ot  = outin + tile_off * EE;
    float*       dt  = out   + tile_off * EE;
    const float* kvt = kv    + ((size_t)bh * NB + mb) * (size_t)(DD * EE);

    const int n0 = wave * 32;            // this wave's 32 output columns

    f32x16 acc0 = {};  // rows  0..31  x cols n0..n0+31
    f32x16 acc1 = {};  // rows 32..63  x cols n0..n0+31

    for (int k0 = 0; k0 < DD; k0 += 16) {
        const int kk = k0 + half * 8;

        // B fragment: KV[kk+j][n0+l31], j=0..7 (K-strided dword loads,
        // lanes 0..31 cover a contiguous 128B row segment per j)
        const float* bp = kvt + (size_t)kk * EE + n0 + l31;
        float b0 = bp[0 * EE], b1 = bp[1 * EE], b2 = bp[2 * EE], b3 = bp[3 * EE];
        float b4 = bp[4 * EE], b5 = bp[5 * EE], b6 = bp[6 * EE], b7 = bp[7 * EE];

        // A fragments: Q[row][kk..kk+7] (contiguous 32B per lane)
        const float4* a0p = (const float4*)(qt + (size_t)l31 * DD + kk);
        const float4* a1p = (const float4*)(qt + (size_t)(l31 + 32) * DD + kk);
        float4 a0lo = a0p[0], a0hi = a0p[1];
        float4 a1lo = a1p[0], a1hi = a1p[1];

        bf16x8 bfrag;
        bfrag[0] = f2bf(b0); bfrag[1] = f2bf(b1); bfrag[2] = f2bf(b2); bfrag[3] = f2bf(b3);
        bfrag[4] = f2bf(b4); bfrag[5] = f2bf(b5); bfrag[6] = f2bf(b6); bfrag[7] = f2bf(b7);
        bf16x8 a0frag = cvt8(a0lo, a0hi);
        bf16x8 a1frag = cvt8(a1lo, a1hi);

        acc0 = __builtin_amdgcn_mfma_f32_32x32x16_bf16(a0frag, bfrag, acc0, 0, 0, 0);
        acc1 = __builtin_amdgcn_mfma_f32_32x32x16_bf16(a1frag, bfrag, acc1, 0, 0, 0);
    }

    // Epilogue: C/D layout for 32x32 MFMA: col = lane&31,
    // row = (reg&3) + 8*(reg>>2) + 4*(lane>>5)
    #pragma unroll
    for (int r = 0; r < 16; ++r) {
        const int row = (r & 3) + 8 * (r >> 2) + 4 * half;   // 0..31
        {
            const int gr = row;                               // tile 0 rows 0..31
            const float dec = __expf(-sh * (float)(gr + 1));
            const size_t idx = (size_t)gr * EE + n0 + l31;
            dt[idx] = ot[idx] + dec * acc0[r];
        }
        {
            const int gr = row + 32;                          // tile 1 rows 32..63
            const float dec = __expf(-sh * (float)(gr + 1));
            const size_t idx = (size_t)gr * EE + n0 + l31;
            dt[idx] = ot[idx] + dec * acc1[r];
        }
    }
}

extern "C" void kernel_launch(void* const* d_in, const int* in_sizes, int n_in,
                              void* d_out, int out_size, void* d_ws, size_t ws_size,
                              hipStream_t stream) {
    const float* q     = (const float*)d_in[0];
    const float* outin = (const float*)d_in[1];
    const float* s     = (const float*)d_in[2];
    const float* kv    = (const float*)d_in[3];
    float*       out   = (float*)d_out;

    const int h = in_sizes[2];                                  // 32
    const long long bh_total = (long long)in_sizes[3] / ((long long)NB * DD * EE); // b*h
    const unsigned grid = (unsigned)(bh_total * NB);            // 8192 blocks

    la_nondiag<<<dim3(grid), dim3(256), 0, stream>>>(q, outin, s, kv, out, h);
}